// Round 1
// baseline (185.623 us; speedup 1.0000x reference)
//
#include <hip/hip_runtime.h>
#include <cstdint>

typedef unsigned short u16;
using short8 = __attribute__((ext_vector_type(8))) short;
using f32x4  = __attribute__((ext_vector_type(4))) float;

// Problem constants (fixed by the reference)
#define T1 512
#define T2 832
#define NH 16
#define DKV 64
#define NPLOC 448   // pos rows used: n in [448, 896)

__device__ __forceinline__ u16 f2b(float f){
  union { float f; uint32_t u; } c; c.f = f;
  uint32_t u = c.u;
  u += 0x7fffu + ((u >> 16) & 1u);   // RNE bf16
  return (u16)(u >> 16);
}

__device__ __forceinline__ void async16(const void* g, void* l){
  __builtin_amdgcn_global_load_lds(
      (const __attribute__((address_space(1))) unsigned int*)g,
      (__attribute__((address_space(3))) unsigned int*)l, 16, 0, 0);
}

// XOR swizzle for bf16 tiles with 128-byte rows ([*][64] bf16)
__device__ __forceinline__ uint32_t swz(uint32_t o){ return o ^ (((o >> 7) & 7u) << 4); }

// ---------------- converts ----------------
__global__ void cvt_bf16(const float* __restrict__ src, u16* __restrict__ dst, int n4){
  int i = blockIdx.x * blockDim.x + threadIdx.x;
  if (i >= n4) return;
  float4 v = ((const float4*)src)[i];
  uint64_t p = (uint64_t)f2b(v.x) | ((uint64_t)f2b(v.y) << 16)
             | ((uint64_t)f2b(v.z) << 32) | ((uint64_t)f2b(v.w) << 48);
  *(uint64_t*)(dst + (size_t)i * 4) = p;
}

// pos_emb rows [448, 896) -> pos_bf rows [0,512) (rows >=448 zero-filled)
__global__ void cvt_pos(const float* __restrict__ src, u16* __restrict__ dst){
  int i = blockIdx.x * blockDim.x + threadIdx.x;   // 131072 threads
  int e = i * 4;
  int row = e >> 10, col = e & 1023;
  float4 v = make_float4(0.f, 0.f, 0.f, 0.f);
  if (row < NPLOC) v = *(const float4*)(src + (size_t)(448 + row) * 1024 + col);
  uint64_t p = (uint64_t)f2b(v.x) | ((uint64_t)f2b(v.y) << 16)
             | ((uint64_t)f2b(v.z) << 32) | ((uint64_t)f2b(v.w) << 48);
  *(uint64_t*)(dst + (size_t)e) = p;
}

// ---------------- GEMM: C = A(MxK) * W(NxK)^T, K=N=1024, m97-style ----------------
// MODE 0: q -> qu/qv bf16 (bias + pos_bias_u/v fused)
// MODE 1: k or v -> f32 cache (d_out) + bf16 att copy
// MODE 2: pos -> p_att bf16 (rows < 448 only, no bias)
// MODE 3: out -> f32 d_out + bias
template<int MODE>
__global__ __launch_bounds__(256) void gemm_bt(
    const u16* __restrict__ A, const u16* __restrict__ W,
    const float* __restrict__ bias, const float* __restrict__ pbu, const float* __restrict__ pbv,
    float* __restrict__ outf, u16* __restrict__ outb, u16* __restrict__ outb2, int co)
{
  __shared__ __align__(16) u16 As[128*32];
  __shared__ __align__(16) u16 Bs[128*32];
  int tid = threadIdx.x;
  int lane = tid & 63, w = tid >> 6;
  int wr = w >> 1, wc = w & 1;
  int m0 = blockIdx.x * 128, n0 = blockIdx.y * 128;
  const int lr = lane & 15, lk = (lane >> 4) * 8;
  f32x4 acc[4][4] = {};

  for (int k0 = 0; k0 < 1024; k0 += 32){
    #pragma unroll
    for (int i = 0; i < 2; ++i){
      int id = i*256 + tid;
      int row = id >> 2, cc = (id & 3) * 8;
      async16(A + (size_t)(m0+row)*1024 + k0 + cc, (u16*)As + id*8);
      async16(W + (size_t)(n0+row)*1024 + k0 + cc, (u16*)Bs + id*8);
    }
    __syncthreads();
    short8 a[4], b[4];
    #pragma unroll
    for (int m = 0; m < 4; ++m) a[m] = *(const short8*)&As[(wr*64 + m*16 + lr)*32 + lk];
    #pragma unroll
    for (int n = 0; n < 4; ++n) b[n] = *(const short8*)&Bs[(wc*64 + n*16 + lr)*32 + lk];
    #pragma unroll
    for (int m = 0; m < 4; ++m)
      #pragma unroll
      for (int n = 0; n < 4; ++n)
        acc[m][n] = __builtin_amdgcn_mfma_f32_16x16x32_bf16(a[m], b[n], acc[m][n], 0, 0, 0);
    __syncthreads();
  }

  #pragma unroll
  for (int m = 0; m < 4; ++m){
    #pragma unroll
    for (int n = 0; n < 4; ++n){
      #pragma unroll
      for (int j = 0; j < 4; ++j){
        int row = m0 + wr*64 + m*16 + (lane >> 4)*4 + j;   // C: row=(lane>>4)*4+reg
        int col = n0 + wc*64 + n*16 + lr;                  //    col=lane&15
        float v = acc[m][n][j];
        if (MODE == 0){
          v += bias[col];
          int h = col >> 6, d = col & 63, b_ = row >> 9, t = row & 511;
          size_t o = ((size_t)((b_*NH + h)*T1 + t))*64 + d;
          outb [o] = f2b(v + pbu[col]);   // pbu is (16,64) flat == indexed by col
          outb2[o] = f2b(v + pbv[col]);
        } else if (MODE == 1){
          v += bias[col];
          int h = col >> 6, d = col & 63;
          int b_ = row / T2, t2 = row - b_*T2;
          size_t base = (size_t)(b_*NH + h)*T2 + t2;
          outf[base*128 + co + d] = v;        // cache (concat k,v) straight into d_out
          outb[base*64 + d] = f2b(v);         // bf16 copy for attention
        } else if (MODE == 2){
          if (row < NPLOC){
            int h = col >> 6, d = col & 63;
            outb[((size_t)h*NPLOC + row)*64 + d] = f2b(v);
          }
        } else {
          outf[(size_t)row*1024 + col] = v + bias[col];
        }
      }
    }
  }
}

// ---------------- attention: one block per (b, h, chunk) ----------------
// window = keys [64c, 64c+384) — exactly the allowed mask, no partial masking.
// bd[t][k] = qv[t] . p[k - t + 511]; locally n_local = jj - r + 63 in [0,448)
__global__ __launch_bounds__(256) void attn_kernel(
    const u16* __restrict__ qu, const u16* __restrict__ qv,
    const u16* __restrict__ katt, const u16* __restrict__ vatt,
    const u16* __restrict__ patt, u16* __restrict__ xout)
{
  __shared__ __align__(16) unsigned char smem[163840];
  // S: 64x384 f32 swizzled (98304 B) | BIG: P/K/Vt (57344 B) | QS: 64x64 bf16 (8192 B)
  u16* BIG = (u16*)(smem + 98304);
  u16* QS  = (u16*)(smem + 98304 + 57344);

  int tid = threadIdx.x, lane = tid & 63, w = tid >> 6;
  int bid = blockIdx.x;
  int c = bid & 7, h = (bid >> 3) & 15, b = bid >> 7;
  int bh = b*NH + h;
  const int lr = lane & 15, lk = (lane >> 4) * 8;

  auto saddr = [&](int r, int cc) -> uint32_t {
    uint32_t o = (uint32_t)(r*384 + cc)*4;
    return o ^ (uint32_t)((r & 7) << 4);
  };
  auto ldq = [&](const u16* base, int row, int col) -> short8 {
    uint32_t o = (uint32_t)(row*64 + col)*2;
    return *(const short8*)((const char*)base + swz(o));
  };

  // ---- stage Qv (8KB) + P (56KB), swizzled via pre-swizzled global source ----
  const u16* qvsrc = qv + ((size_t)bh*T1 + c*64)*64;
  const u16* psrc  = patt + (size_t)h*NPLOC*64;
  #pragma unroll
  for (int i = 0; i < 2; ++i){ uint32_t o = (uint32_t)(i*256 + tid)*16; async16((const char*)qvsrc + swz(o), (char*)QS + o); }
  for (int i = 0; i < 14; ++i){ uint32_t o = (uint32_t)(i*256 + tid)*16; async16((const char*)psrc + swz(o), (char*)BIG + o); }
  __syncthreads();

  // ---- BD: rows [16w,16w+16) x 448 cols, scatter into S (each S elem written once) ----
  {
    short8 a0 = ldq(QS, 16*w + lr, lk);
    short8 a1 = ldq(QS, 16*w + lr, 32 + lk);
    for (int nt = 0; nt < 28; ++nt){
      f32x4 acc = {0.f, 0.f, 0.f, 0.f};
      short8 b0 = ldq(BIG, nt*16 + lr, lk);
      short8 b1 = ldq(BIG, nt*16 + lr, 32 + lk);
      acc = __builtin_amdgcn_mfma_f32_16x16x32_bf16(a0, b0, acc, 0, 0, 0);
      acc = __builtin_amdgcn_mfma_f32_16x16x32_bf16(a1, b1, acc, 0, 0, 0);
      int nl = nt*16 + lr;
      #pragma unroll
      for (int j = 0; j < 4; ++j){
        int r = 16*w + (lane >> 4)*4 + j;
        int jj = nl + r - 63;
        if (jj >= 0 && jj < 384) *(float*)(smem + saddr(r, jj)) = acc[j];
      }
    }
  }
  __syncthreads();

  // ---- stage Qu + K window ----
  const u16* qusrc = qu + ((size_t)bh*T1 + c*64)*64;
  const u16* ksrc  = katt + ((size_t)bh*T2 + c*64)*64;   // 384x64 contiguous
  #pragma unroll
  for (int i = 0; i < 2; ++i){ uint32_t o = (uint32_t)(i*256 + tid)*16; async16((const char*)qusrc + swz(o), (char*)QS + o); }
  for (int i = 0; i < 12; ++i){ uint32_t o = (uint32_t)(i*256 + tid)*16; async16((const char*)ksrc + swz(o), (char*)BIG + o); }
  __syncthreads();

  // ---- AC: add q_u . k into S ----
  {
    short8 a0 = ldq(QS, 16*w + lr, lk);
    short8 a1 = ldq(QS, 16*w + lr, 32 + lk);
    for (int nt = 0; nt < 24; ++nt){
      f32x4 acc = {0.f, 0.f, 0.f, 0.f};
      short8 b0 = ldq(BIG, nt*16 + lr, lk);
      short8 b1 = ldq(BIG, nt*16 + lr, 32 + lk);
      acc = __builtin_amdgcn_mfma_f32_16x16x32_bf16(a0, b0, acc, 0, 0, 0);
      acc = __builtin_amdgcn_mfma_f32_16x16x32_bf16(a1, b1, acc, 0, 0, 0);
      int cc = nt*16 + lr;
      #pragma unroll
      for (int j = 0; j < 4; ++j){
        int r = 16*w + (lane >> 4)*4 + j;
        float* p = (float*)(smem + saddr(r, cc));
        *p += acc[j];
      }
    }
  }
  __syncthreads();

  // ---- softmax: 4 lanes per row, scale 1/sqrt(64) ----
  {
    int r = tid >> 2, q = tid & 3;
    float v[96]; float mx = -1e30f;
    #pragma unroll
    for (int i = 0; i < 96; ++i){ v[i] = *(float*)(smem + saddr(r, q + 4*i)); mx = fmaxf(mx, v[i]); }
    mx = fmaxf(mx, __shfl_xor(mx, 1)); mx = fmaxf(mx, __shfl_xor(mx, 2));
    float s = 0.f;
    #pragma unroll
    for (int i = 0; i < 96; ++i){ v[i] = __expf((v[i] - mx) * 0.125f); s += v[i]; }
    s += __shfl_xor(s, 1); s += __shfl_xor(s, 2);
    float inv = 1.f / s;
    #pragma unroll
    for (int i = 0; i < 96; ++i){ *(float*)(smem + saddr(r, q + 4*i)) = v[i] * inv; }
  }
  __syncthreads();

  // ---- stage V transposed: Vt[64][392] bf16 (pad 8 -> 2-way banks) ----
  {
    const u16* vw = vatt + ((size_t)bh*T2 + c*64)*64;
    for (int i = 0; i < 12; ++i){
      int e = (i*256 + tid) * 8;
      int kk = e >> 6, d0 = e & 63;
      uint4 vv = *(const uint4*)(vw + (size_t)kk*64 + d0);
      u16 u[8] = { (u16)(vv.x & 0xffff), (u16)(vv.x >> 16), (u16)(vv.y & 0xffff), (u16)(vv.y >> 16),
                   (u16)(vv.z & 0xffff), (u16)(vv.z >> 16), (u16)(vv.w & 0xffff), (u16)(vv.w >> 16) };
      #pragma unroll
      for (int j = 0; j < 8; ++j) BIG[(d0 + j)*392 + kk] = u[j];
    }
  }
  __syncthreads();

  // ---- PV: O[16][64] per wave = P[16][384] . V[384][64] ----
  {
    f32x4 acc[4] = {};
    for (int kt = 0; kt < 12; ++kt){
      int r = 16*w + lr;
      float4 f0 = *(float4*)(smem + saddr(r, kt*32 + lk));
      float4 f1 = *(float4*)(smem + saddr(r, kt*32 + lk + 4));
      short8 a;
      a[0]=f2b(f0.x); a[1]=f2b(f0.y); a[2]=f2b(f0.z); a[3]=f2b(f0.w);
      a[4]=f2b(f1.x); a[5]=f2b(f1.y); a[6]=f2b(f1.z); a[7]=f2b(f1.w);
      #pragma unroll
      for (int n = 0; n < 4; ++n){
        short8 bb = *(const short8*)&BIG[(n*16 + lr)*392 + kt*32 + lk];
        acc[n] = __builtin_amdgcn_mfma_f32_16x16x32_bf16(a, bb, acc[n], 0, 0, 0);
      }
    }
    #pragma unroll
    for (int n = 0; n < 4; ++n)
      #pragma unroll
      for (int j = 0; j < 4; ++j){
        int r = 16*w + (lane >> 4)*4 + j;
        int t = c*64 + r;
        int d = n*16 + lr;
        xout[((size_t)b*T1 + t)*1024 + h*64 + d] = f2b(acc[n][j]);
      }
  }
}

// ---------------- launch ----------------
extern "C" void kernel_launch(void* const* d_in, const int* in_sizes, int n_in,
                              void* d_out, int out_size, void* d_ws, size_t ws_size,
                              hipStream_t stream)
{
  const float* query = (const float*)d_in[0];
  const float* key   = (const float*)d_in[1];
  const float* value = (const float*)d_in[2];
  const float* pos   = (const float*)d_in[3];
  const float* Wq  = (const float*)d_in[4];
  const float* bq  = (const float*)d_in[5];
  const float* Wk  = (const float*)d_in[6];
  const float* bk  = (const float*)d_in[7];
  const float* Wv  = (const float*)d_in[8];
  const float* bv  = (const float*)d_in[9];
  const float* Wp  = (const float*)d_in[10];
  const float* Wo  = (const float*)d_in[11];
  const float* bo  = (const float*)d_in[12];
  const float* pbu = (const float*)d_in[13];
  const float* pbv = (const float*)d_in[14];
  // d_in[15] mask: recomputed analytically (window structure); [16],[17] scalars: compile-time.

  float* out   = (float*)d_out;
  float* cache = out + 2097152;                 // (4,16,832,128) f32

  u16* ws     = (u16*)d_ws;
  u16* q_bf   = ws;                              // 2048x1024
  u16* key_bf = ws + 2097152;                    // 3328x1024
  u16* val_bf = ws + 5505024;                    // 3328x1024
  u16* pos_bf = ws + 8912896;                    // 512x1024 (448 used)
  u16* Wq_bf  = ws + 9437184;
  u16* Wk_bf  = ws + 10485760;
  u16* Wv_bf  = ws + 11534336;
  u16* Wp_bf  = ws + 12582912;
  u16* Wo_bf  = ws + 13631488;
  u16* qu_bf  = ws + 14680064;                   // (b,h,t,d)
  u16* qv_bf  = ws + 16777216;
  u16* katt   = ws + 18874368;                   // (b,h,t2,d)
  u16* vatt   = ws + 22282240;
  u16* patt   = ws + 25690112;                   // (h,448,d)
  u16* x_bf   = ws + 26148864;                   // 2048x1024
  // total 28246016 u16 = 56.5 MB

  cvt_bf16<<<2048, 256, 0, stream>>>(query, q_bf, 524288);
  cvt_bf16<<<3328, 256, 0, stream>>>(key,   key_bf, 851968);
  cvt_bf16<<<3328, 256, 0, stream>>>(value, val_bf, 851968);
  cvt_bf16<<<1024, 256, 0, stream>>>(Wq, Wq_bf, 262144);
  cvt_bf16<<<1024, 256, 0, stream>>>(Wk, Wk_bf, 262144);
  cvt_bf16<<<1024, 256, 0, stream>>>(Wv, Wv_bf, 262144);
  cvt_bf16<<<1024, 256, 0, stream>>>(Wp, Wp_bf, 262144);
  cvt_bf16<<<1024, 256, 0, stream>>>(Wo, Wo_bf, 262144);
  cvt_pos<<<512, 256, 0, stream>>>(pos, pos_bf);

  gemm_bt<0><<<dim3(16,8), 256, 0, stream>>>(q_bf,   Wq_bf, bq, pbu, pbv, nullptr, qu_bf, qv_bf, 0);
  gemm_bt<1><<<dim3(26,8), 256, 0, stream>>>(key_bf, Wk_bf, bk, nullptr, nullptr, cache, katt, nullptr, 0);
  gemm_bt<1><<<dim3(26,8), 256, 0, stream>>>(val_bf, Wv_bf, bv, nullptr, nullptr, cache, vatt, nullptr, 64);
  gemm_bt<2><<<dim3(4,8),  256, 0, stream>>>(pos_bf, Wp_bf, nullptr, nullptr, nullptr, nullptr, patt, nullptr, 0);

  attn_kernel<<<512, 256, 0, stream>>>(qu_bf, qv_bf, katt, vatt, patt, x_bf);

  gemm_bt<3><<<dim3(16,8), 256, 0, stream>>>(x_bf, Wo_bf, bo, nullptr, nullptr, out, nullptr, nullptr, 0);
}

// Round 2
// 121.434 us; speedup vs baseline: 1.5286x; 1.5286x over previous
//
#include <hip/hip_runtime.h>
#include <cstdint>

typedef unsigned short u16;
using short8 = __attribute__((ext_vector_type(8))) short;
using f32x4  = __attribute__((ext_vector_type(4))) float;

#define T1 512
#define T2 832
#define NH 16
#define NPLOC 448

__device__ __forceinline__ u16 f2b(float f){
  union { float f; uint32_t u; } c; c.f = f;
  uint32_t u = c.u;
  u += 0x7fffu + ((u >> 16) & 1u);   // RNE bf16
  return (u16)(u >> 16);
}
__device__ __forceinline__ float b2f(u16 b){
  union { uint32_t u; float f; } c; c.u = (uint32_t)b << 16; return c.f;
}
__device__ __forceinline__ void async16(const void* g, void* l){
  __builtin_amdgcn_global_load_lds(
      (const __attribute__((address_space(1))) unsigned int*)g,
      (__attribute__((address_space(3))) unsigned int*)l, 16, 0, 0);
}

// ---------------- fused f32 -> bf16 convert (one launch) ----------------
struct CvtSeg { const float* src; u16* dst; int nblk; };  // nblk blocks of 256 float4s
struct CvtArgs { CvtSeg s[9]; };

__global__ __launch_bounds__(256) void cvt_all(CvtArgs a){
  int rel = blockIdx.x, seg = 0;
  while (rel >= a.s[seg].nblk){ rel -= a.s[seg].nblk; ++seg; }
  int i = rel * 256 + threadIdx.x;
  float4 v = ((const float4*)a.s[seg].src)[i];
  uint64_t p = (uint64_t)f2b(v.x) | ((uint64_t)f2b(v.y) << 16)
             | ((uint64_t)f2b(v.z) << 32) | ((uint64_t)f2b(v.w) << 48);
  *(uint64_t*)(a.s[seg].dst + (size_t)i * 4) = p;
}

// ---------------- shared GEMM core: C = A(Mx1024) * W(1024x1024)^T ----------------
__device__ __forceinline__ void gemm_core(const u16* __restrict__ A, const u16* __restrict__ W,
    int m0, int n0, int tid, u16* As, u16* Bs, f32x4 acc[4][4])
{
  int lane = tid & 63;
  int wr = (tid >> 6) >> 1, wc = (tid >> 6) & 1;
  const int lr = lane & 15, lk = (lane >> 4) * 8;
  for (int k0 = 0; k0 < 1024; k0 += 32){
    #pragma unroll
    for (int i = 0; i < 2; ++i){
      int id = i*256 + tid;
      int row = id >> 2, cc = (id & 3) * 8;
      async16(A + (size_t)(m0+row)*1024 + k0 + cc, As + id*8);
      async16(W + (size_t)(n0+row)*1024 + k0 + cc, Bs + id*8);
    }
    __syncthreads();
    short8 a[4], b[4];
    #pragma unroll
    for (int m = 0; m < 4; ++m) a[m] = *(const short8*)&As[(wr*64 + m*16 + lr)*32 + lk];
    #pragma unroll
    for (int n = 0; n < 4; ++n) b[n] = *(const short8*)&Bs[(wc*64 + n*16 + lr)*32 + lk];
    #pragma unroll
    for (int m = 0; m < 4; ++m)
      #pragma unroll
      for (int n = 0; n < 4; ++n)
        acc[m][n] = __builtin_amdgcn_mfma_f32_16x16x32_bf16(a[m], b[n], acc[m][n], 0, 0, 0);
    __syncthreads();
  }
}

// ---------------- fused q/k/v/pos projection GEMMs (one launch, 576 blocks) ----------------
struct G4Args {
  const u16 *q, *k, *v, *p;
  const u16 *Wq, *Wk, *Wv, *Wp;
  const float *bq, *bk, *bv, *pbu, *pbv;
  u16 *qu, *qv2, *katt, *vatt, *patt;
  float *cache;
};

__global__ __launch_bounds__(256) void gemm4(G4Args g){
  __shared__ __align__(16) u16 As[128*32];
  __shared__ __align__(16) u16 Bs[128*32];
  int bid0 = blockIdx.x;
  int bid = (bid0 & 7) * 72 + (bid0 >> 3);   // XCD swizzle (576 = 8*72)
  int tid = threadIdx.x;
  int mode, mb; const u16 *A, *W;
  if (bid < 128)      { mode = 0; mb = bid >> 3;         A = g.q; W = g.Wq; }
  else if (bid < 336) { mode = 1; mb = (bid - 128) >> 3; A = g.k; W = g.Wk; }
  else if (bid < 544) { mode = 2; mb = (bid - 336) >> 3; A = g.v; W = g.Wv; }
  else                { mode = 3; mb = (bid - 544) >> 3; A = g.p; W = g.Wp; }
  int m0 = mb * 128, n0 = (bid & 7) * 128;
  f32x4 acc[4][4] = {};
  gemm_core(A, W, m0, n0, tid, As, Bs, acc);

  int lane = tid & 63;
  int wr = (tid >> 6) >> 1, wc = (tid >> 6) & 1;
  const int lr = lane & 15;
  #pragma unroll
  for (int m = 0; m < 4; ++m){
    #pragma unroll
    for (int n = 0; n < 4; ++n){
      #pragma unroll
      for (int j = 0; j < 4; ++j){
        int row = m0 + wr*64 + m*16 + (lane >> 4)*4 + j;
        int col = n0 + wc*64 + n*16 + lr;
        float vv = acc[m][n][j];
        if (mode == 0){
          vv += g.bq[col];
          int h = col >> 6, d = col & 63, b_ = row >> 9, t = row & 511;
          size_t o = ((size_t)((b_*NH + h)*T1 + t))*64 + d;
          g.qu [o] = f2b(vv + g.pbu[col]);
          g.qv2[o] = f2b(vv + g.pbv[col]);
        } else if (mode == 1 || mode == 2){
          vv += (mode == 1 ? g.bk : g.bv)[col];
          int h = col >> 6, d = col & 63;
          int b_ = row / T2, t2 = row - b_*T2;
          size_t base = (size_t)(b_*NH + h)*T2 + t2;
          g.cache[base*128 + (mode == 2 ? 64 : 0) + d] = vv;
          (mode == 1 ? g.katt : g.vatt)[base*64 + d] = f2b(vv);
        } else {
          if (row < NPLOC){
            int h = col >> 6, d = col & 63;
            g.patt[((size_t)h*NPLOC + row)*64 + d] = f2b(vv);
          }
        }
      }
    }
  }
}

// ---------------- output GEMM ----------------
__global__ __launch_bounds__(256) void gemm_out(const u16* __restrict__ A, const u16* __restrict__ W,
                                                const float* __restrict__ bias, float* __restrict__ out){
  __shared__ __align__(16) u16 As[128*32];
  __shared__ __align__(16) u16 Bs[128*32];
  int bid0 = blockIdx.x;
  int bid = (bid0 & 7) * 16 + (bid0 >> 3);   // 128 = 8*16
  int m0 = (bid >> 3) * 128, n0 = (bid & 7) * 128;
  int tid = threadIdx.x;
  f32x4 acc[4][4] = {};
  gemm_core(A, W, m0, n0, tid, As, Bs, acc);
  int lane = tid & 63;
  int wr = (tid >> 6) >> 1, wc = (tid >> 6) & 1;
  const int lr = lane & 15;
  #pragma unroll
  for (int m = 0; m < 4; ++m)
    #pragma unroll
    for (int n = 0; n < 4; ++n)
      #pragma unroll
      for (int j = 0; j < 4; ++j){
        int row = m0 + wr*64 + m*16 + (lane >> 4)*4 + j;
        int col = n0 + wc*64 + n*16 + lr;
        out[(size_t)row*1024 + col] = acc[m][n][j] + bias[col];
      }
}

// ---------------- attention v2: 76KB LDS -> 2 blocks/CU ----------------
// Per block (b,h,c): 64 q-rows, window K[64c, 64c+384), pos rows [0,448).
// SB: bf16 [64][384] swizzled (bd scores, then P). AC+softmax fully in registers.
__global__ __launch_bounds__(256, 2) void attn_v2(
    const u16* __restrict__ qu, const u16* __restrict__ qv,
    const u16* __restrict__ katt, const u16* __restrict__ vatt,
    const u16* __restrict__ patt, u16* __restrict__ xout)
{
  __shared__ __align__(16) u16 SB[64*384];    // 49152 B
  __shared__ __align__(16) u16 STG[14336];    // 28672 B staging (P/K chunks, Vt)
  int tid = threadIdx.x, lane = tid & 63, w = tid >> 6;
  int bid0 = blockIdx.x;
  int bid = (bid0 & 7) * 64 + (bid0 >> 3);    // XCD swizzle (512 = 8*64)
  int c = bid & 7, h = (bid >> 3) & 15, b = bid >> 7;
  int bh = b*NH + h;
  const int lr = lane & 15, g = lane >> 4, lk = g * 8;

  auto sb_off = [&](int r, int cc) -> uint32_t {
    return ((uint32_t)(r*384 + cc)*2) ^ ((uint32_t)(r & 15) << 4);   // 4-bit XOR, 768B rows
  };
  auto stg_swz = [&](uint32_t o) -> uint32_t { return o ^ (((o >> 7) & 7u) << 4); };  // 128B rows
  auto vt_off = [&](int d, int kk) -> uint32_t {
    return ((uint32_t)(d*192 + kk)*2) ^ ((uint32_t)(((d & 7) ^ ((d >> 3) & 7))) << 4); // 384B rows
  };

  // Q fragments straight to registers (each wave owns rows [16w, 16w+16))
  int qrow = 16*w + lr;
  const u16* qub = qu + ((size_t)bh*T1 + c*64 + qrow)*64;
  const u16* qvb = qv + ((size_t)bh*T1 + c*64 + qrow)*64;
  short8 qu0 = *(const short8*)(qub + lk);
  short8 qu1 = *(const short8*)(qub + 32 + lk);
  short8 qv0 = *(const short8*)(qvb + lk);
  short8 qv1 = *(const short8*)(qvb + 32 + lk);

  // ---- BD: qv . p, scattered (rel-shift) into SB as bf16; 2 P-chunks of 224 rows ----
  const char* psrc = (const char*)(patt + (size_t)h*NPLOC*64);
  for (int pc = 0; pc < 2; ++pc){
    #pragma unroll
    for (int i = 0; i < 7; ++i){
      uint32_t o = (uint32_t)(i*256 + tid)*16;
      async16(psrc + pc*28672 + stg_swz(o), (char*)STG + o);
    }
    __syncthreads();
    for (int nt = 0; nt < 14; ++nt){
      uint32_t bo = (uint32_t)((nt*16 + lr)*64)*2;
      short8 b0 = *(const short8*)((const char*)STG + stg_swz(bo + lk*2));
      short8 b1 = *(const short8*)((const char*)STG + stg_swz(bo + (32 + lk)*2));
      f32x4 acc = {0.f,0.f,0.f,0.f};
      acc = __builtin_amdgcn_mfma_f32_16x16x32_bf16(qv0, b0, acc, 0, 0, 0);
      acc = __builtin_amdgcn_mfma_f32_16x16x32_bf16(qv1, b1, acc, 0, 0, 0);
      int nl = pc*224 + nt*16 + lr;
      #pragma unroll
      for (int j = 0; j < 4; ++j){
        int r = 16*w + g*4 + j;
        int jj = nl + r - 63;
        if (jj >= 0 && jj < 384) *(u16*)((char*)SB + sb_off(r, jj)) = f2b(acc[j]);
      }
    }
    __syncthreads();
  }

  // ---- AC: qu . k into registers; 2 K-chunks of 192 rows ----
  const char* ksrc = (const char*)(katt + ((size_t)bh*T2 + c*64)*64);
  f32x4 accs[24];
  #pragma unroll
  for (int t = 0; t < 24; ++t) accs[t] = (f32x4){0.f,0.f,0.f,0.f};
  #pragma unroll
  for (int kc = 0; kc < 2; ++kc){
    #pragma unroll
    for (int i = 0; i < 6; ++i){
      uint32_t o = (uint32_t)(i*256 + tid)*16;
      async16(ksrc + kc*24576 + stg_swz(o), (char*)STG + o);
    }
    __syncthreads();
    #pragma unroll
    for (int nt = 0; nt < 12; ++nt){
      uint32_t bo = (uint32_t)((nt*16 + lr)*64)*2;
      short8 b0 = *(const short8*)((const char*)STG + stg_swz(bo + lk*2));
      short8 b1 = *(const short8*)((const char*)STG + stg_swz(bo + (32 + lk)*2));
      int t = kc*12 + nt;
      accs[t] = __builtin_amdgcn_mfma_f32_16x16x32_bf16(qu0, b0, accs[t], 0, 0, 0);
      accs[t] = __builtin_amdgcn_mfma_f32_16x16x32_bf16(qu1, b1, accs[t], 0, 0, 0);
    }
    __syncthreads();
  }

  // ---- add bd (from SB), softmax in registers, write P back to SB as bf16 ----
  #pragma unroll
  for (int t = 0; t < 24; ++t)
    #pragma unroll
    for (int j = 0; j < 4; ++j){
      int r = 16*w + g*4 + j, cc = t*16 + lr;
      accs[t][j] += b2f(*(const u16*)((const char*)SB + sb_off(r, cc)));
    }
  float mx[4] = {-1e30f,-1e30f,-1e30f,-1e30f};
  #pragma unroll
  for (int t = 0; t < 24; ++t)
    #pragma unroll
    for (int j = 0; j < 4; ++j) mx[j] = fmaxf(mx[j], accs[t][j]);
  #pragma unroll
  for (int j = 0; j < 4; ++j){
    mx[j] = fmaxf(mx[j], __shfl_xor(mx[j], 1));
    mx[j] = fmaxf(mx[j], __shfl_xor(mx[j], 2));
    mx[j] = fmaxf(mx[j], __shfl_xor(mx[j], 4));
    mx[j] = fmaxf(mx[j], __shfl_xor(mx[j], 8));
  }
  float sm[4] = {0.f,0.f,0.f,0.f};
  #pragma unroll
  for (int t = 0; t < 24; ++t)
    #pragma unroll
    for (int j = 0; j < 4; ++j){
      accs[t][j] = __expf((accs[t][j] - mx[j]) * 0.125f);
      sm[j] += accs[t][j];
    }
  #pragma unroll
  for (int j = 0; j < 4; ++j){
    sm[j] += __shfl_xor(sm[j], 1);
    sm[j] += __shfl_xor(sm[j], 2);
    sm[j] += __shfl_xor(sm[j], 4);
    sm[j] += __shfl_xor(sm[j], 8);
    sm[j] = 1.f / sm[j];
  }
  #pragma unroll
  for (int t = 0; t < 24; ++t)
    #pragma unroll
    for (int j = 0; j < 4; ++j){
      int r = 16*w + g*4 + j, cc = t*16 + lr;
      *(u16*)((char*)SB + sb_off(r, cc)) = f2b(accs[t][j] * sm[j]);
    }
  __syncthreads();

  // ---- PV: O = P . V ; 2 V k-chunks of 192, V transposed into STG ----
  f32x4 acco[4] = {};
  #pragma unroll
  for (int vc = 0; vc < 2; ++vc){
    if (vc) __syncthreads();
    const u16* vb = vatt + ((size_t)bh*T2 + c*64 + vc*192)*64;
    #pragma unroll
    for (int i = 0; i < 6; ++i){
      int e = (i*256 + tid)*8;
      int kk = e >> 6, d0 = e & 63;
      uint4 vv4 = *(const uint4*)(vb + (size_t)kk*64 + d0);
      u16 uu[8] = { (u16)(vv4.x & 0xffff), (u16)(vv4.x >> 16), (u16)(vv4.y & 0xffff), (u16)(vv4.y >> 16),
                    (u16)(vv4.z & 0xffff), (u16)(vv4.z >> 16), (u16)(vv4.w & 0xffff), (u16)(vv4.w >> 16) };
      #pragma unroll
      for (int j = 0; j < 8; ++j)
        *(u16*)((char*)STG + vt_off(d0 + j, kk)) = uu[j];
    }
    __syncthreads();
    #pragma unroll
    for (int kt = 0; kt < 6; ++kt){
      short8 a = *(const short8*)((const char*)SB + sb_off(16*w + lr, vc*192 + kt*32 + lk));
      #pragma unroll
      for (int n = 0; n < 4; ++n){
        short8 bb = *(const short8*)((const char*)STG + vt_off(n*16 + lr, kt*32 + lk));
        acco[n] = __builtin_amdgcn_mfma_f32_16x16x32_bf16(a, bb, acco[n], 0, 0, 0);
      }
    }
  }

  #pragma unroll
  for (int n = 0; n < 4; ++n)
    #pragma unroll
    for (int j = 0; j < 4; ++j){
      int r = 16*w + g*4 + j;
      int t = c*64 + r, d = n*16 + lr;
      xout[((size_t)b*T1 + t)*1024 + h*64 + d] = f2b(acco[n][j]);
    }
}

// ---------------- launch ----------------
extern "C" void kernel_launch(void* const* d_in, const int* in_sizes, int n_in,
                              void* d_out, int out_size, void* d_ws, size_t ws_size,
                              hipStream_t stream)
{
  const float* query = (const float*)d_in[0];
  const float* key   = (const float*)d_in[1];
  const float* value = (const float*)d_in[2];
  const float* pos   = (const float*)d_in[3];
  const float* Wq  = (const float*)d_in[4];
  const float* bq  = (const float*)d_in[5];
  const float* Wk  = (const float*)d_in[6];
  const float* bk  = (const float*)d_in[7];
  const float* Wv  = (const float*)d_in[8];
  const float* bv  = (const float*)d_in[9];
  const float* Wp  = (const float*)d_in[10];
  const float* Wo  = (const float*)d_in[11];
  const float* bo  = (const float*)d_in[12];
  const float* pbu = (const float*)d_in[13];
  const float* pbv = (const float*)d_in[14];

  float* out   = (float*)d_out;
  float* cache = out + 2097152;

  u16* ws     = (u16*)d_ws;
  u16* q_bf   = ws;
  u16* key_bf = ws + 2097152;
  u16* val_bf = ws + 5505024;
  u16* pos_bf = ws + 8912896;
  u16* Wq_bf  = ws + 9437184;
  u16* Wk_bf  = ws + 10485760;
  u16* Wv_bf  = ws + 11534336;
  u16* Wp_bf  = ws + 12582912;
  u16* Wo_bf  = ws + 13631488;
  u16* qu_bf  = ws + 14680064;
  u16* qv_bf  = ws + 16777216;
  u16* katt   = ws + 18874368;
  u16* vatt   = ws + 22282240;
  u16* patt   = ws + 25690112;
  u16* x_bf   = ws + 26148864;

  CvtArgs ca;
  ca.s[0] = { query,            q_bf,   2048 };
  ca.s[1] = { key,              key_bf, 3328 };
  ca.s[2] = { value,            val_bf, 3328 };
  ca.s[3] = { Wq,               Wq_bf,  1024 };
  ca.s[4] = { Wk,               Wk_bf,  1024 };
  ca.s[5] = { Wv,               Wv_bf,  1024 };
  ca.s[6] = { Wp,               Wp_bf,  1024 };
  ca.s[7] = { Wo,               Wo_bf,  1024 };
  ca.s[8] = { pos + 448*1024,   pos_bf, 448 };   // pos rows [448,896) -> rows [0,448)
  cvt_all<<<14272, 256, 0, stream>>>(ca);

  G4Args ga;
  ga.q = q_bf; ga.k = key_bf; ga.v = val_bf; ga.p = pos_bf;
  ga.Wq = Wq_bf; ga.Wk = Wk_bf; ga.Wv = Wv_bf; ga.Wp = Wp_bf;
  ga.bq = bq; ga.bk = bk; ga.bv = bv; ga.pbu = pbu; ga.pbv = pbv;
  ga.qu = qu_bf; ga.qv2 = qv_bf; ga.katt = katt; ga.vatt = vatt; ga.patt = patt;
  ga.cache = cache;
  gemm4<<<576, 256, 0, stream>>>(ga);

  attn_v2<<<512, 256, 0, stream>>>(qu_bf, qv_bf, katt, vatt, patt, x_bf);

  gemm_out<<<128, 256, 0, stream>>>(x_bf, Wo_bf, bo, out);
}

// Round 3
// 116.849 us; speedup vs baseline: 1.5886x; 1.0392x over previous
//
#include <hip/hip_runtime.h>
#include <cstdint>

typedef unsigned short u16;
using short8 = __attribute__((ext_vector_type(8))) short;
using f32x4  = __attribute__((ext_vector_type(4))) float;

#define T1 512
#define T2 832
#define NH 16
#define NPLOC 448

__device__ __forceinline__ u16 f2b(float f){
  union { float f; uint32_t u; } c; c.f = f;
  uint32_t u = c.u;
  u += 0x7fffu + ((u >> 16) & 1u);   // RNE bf16
  return (u16)(u >> 16);
}
__device__ __forceinline__ float b2f(u16 b){
  union { uint32_t u; float f; } c; c.u = (uint32_t)b << 16; return c.f;
}
__device__ __forceinline__ void async16(const void* g, void* l){
  __builtin_amdgcn_global_load_lds(
      (const __attribute__((address_space(1))) unsigned int*)g,
      (__attribute__((address_space(3))) unsigned int*)l, 16, 0, 0);
}

// ---------------- fused f32 -> bf16 convert (one launch) ----------------
struct CvtSeg { const float* src; u16* dst; int nblk; };
struct CvtArgs { CvtSeg s[9]; };

__global__ __launch_bounds__(256) void cvt_all(CvtArgs a){
  int rel = blockIdx.x, seg = 0;
  while (rel >= a.s[seg].nblk){ rel -= a.s[seg].nblk; ++seg; }
  int i = rel * 256 + threadIdx.x;
  float4 v = ((const float4*)a.s[seg].src)[i];
  uint64_t p = (uint64_t)f2b(v.x) | ((uint64_t)f2b(v.y) << 16)
             | ((uint64_t)f2b(v.z) << 32) | ((uint64_t)f2b(v.w) << 48);
  *(uint64_t*)(a.s[seg].dst + (size_t)i * 4) = p;
}

// ---------------- 2-phase double-buffered GEMM core ----------------
// C = A(Mx1024) * W(1024x1024)^T, 128x128 tile, BK=32, T3-minimal pipeline.
__device__ __forceinline__ void gemm_core(const u16* __restrict__ A, const u16* __restrict__ W,
    int m0, int n0, int tid, f32x4 acc[4][4])
{
  __shared__ __align__(16) u16 As0[4096];
  __shared__ __align__(16) u16 As1[4096];
  __shared__ __align__(16) u16 Bs0[4096];
  __shared__ __align__(16) u16 Bs1[4096];

  int lane = tid & 63;
  int wr = (tid >> 6) >> 1, wc = (tid >> 6) & 1;
  const int lr = lane & 15, lk = (lane >> 4) * 8;
  int srow = tid >> 2, scc = (tid & 3) * 8;
  const u16* Ab = A + (size_t)(m0 + srow) * 1024 + scc;
  const u16* Wb = W + (size_t)(n0 + srow) * 1024 + scc;

  auto stage = [&](int k0, u16* as, u16* bs){
    async16(Ab + k0,         as + tid*8);
    async16(Ab + k0 + 65536, as + 2048 + tid*8);   // rows +64
    async16(Wb + k0,         bs + tid*8);
    async16(Wb + k0 + 65536, bs + 2048 + tid*8);
  };
  auto compute = [&](const u16* as, const u16* bs){
    short8 a[4], b[4];
    #pragma unroll
    for (int m = 0; m < 4; ++m) a[m] = *(const short8*)&as[(wr*64 + m*16 + lr)*32 + lk];
    #pragma unroll
    for (int n = 0; n < 4; ++n) b[n] = *(const short8*)&bs[(wc*64 + n*16 + lr)*32 + lk];
    asm volatile("s_waitcnt lgkmcnt(0)" ::: "memory");
    __builtin_amdgcn_sched_barrier(0);
    #pragma unroll
    for (int m = 0; m < 4; ++m)
      #pragma unroll
      for (int n = 0; n < 4; ++n)
        acc[m][n] = __builtin_amdgcn_mfma_f32_16x16x32_bf16(a[m], b[n], acc[m][n], 0, 0, 0);
  };

  stage(0, As0, Bs0);
  __syncthreads();                       // vmcnt(0) drain + barrier (prologue)
  for (int k0 = 0; k0 < 1024; k0 += 64){
    stage(k0 + 32, As1, Bs1);            // prefetch odd tile
    __builtin_amdgcn_sched_barrier(0);
    compute(As0, Bs0);                   // compute even tile (loads in flight)
    __syncthreads();
    if (k0 + 64 < 1024) stage(k0 + 64, As0, Bs0);
    __builtin_amdgcn_sched_barrier(0);
    compute(As1, Bs1);
    __syncthreads();
  }
}

// ---------------- fused q/k/v/pos projection GEMMs ----------------
struct G4Args {
  const u16 *q, *k, *v, *p;
  const u16 *Wq, *Wk, *Wv, *Wp;
  const float *bq, *bk, *bv, *pbu, *pbv;
  u16 *qu, *qv2, *katt, *vatt, *patt;
  float *cache;
};

__global__ __launch_bounds__(256) void gemm4(G4Args g){
  int bid0 = blockIdx.x;
  int bid = (bid0 & 7) * 72 + (bid0 >> 3);   // XCD swizzle (576 = 8*72)
  int tid = threadIdx.x;
  int mode, mb; const u16 *A, *W;
  if (bid < 128)      { mode = 0; mb = bid >> 3;         A = g.q; W = g.Wq; }
  else if (bid < 336) { mode = 1; mb = (bid - 128) >> 3; A = g.k; W = g.Wk; }
  else if (bid < 544) { mode = 2; mb = (bid - 336) >> 3; A = g.v; W = g.Wv; }
  else                { mode = 3; mb = (bid - 544) >> 3; A = g.p; W = g.Wp; }
  int m0 = mb * 128, n0 = (bid & 7) * 128;
  f32x4 acc[4][4] = {};
  gemm_core(A, W, m0, n0, tid, acc);

  int lane = tid & 63;
  int wr = (tid >> 6) >> 1, wc = (tid >> 6) & 1;
  const int lr = lane & 15;
  #pragma unroll
  for (int m = 0; m < 4; ++m){
    #pragma unroll
    for (int n = 0; n < 4; ++n){
      #pragma unroll
      for (int j = 0; j < 4; ++j){
        int row = m0 + wr*64 + m*16 + (lane >> 4)*4 + j;
        int col = n0 + wc*64 + n*16 + lr;
        float vv = acc[m][n][j];
        if (mode == 0){
          vv += g.bq[col];
          int h = col >> 6, d = col & 63, b_ = row >> 9, t = row & 511;
          size_t o = ((size_t)((b_*NH + h)*T1 + t))*64 + d;
          g.qu [o] = f2b(vv + g.pbu[col]);
          g.qv2[o] = f2b(vv + g.pbv[col]);
        } else if (mode == 1 || mode == 2){
          vv += (mode == 1 ? g.bk : g.bv)[col];
          int h = col >> 6, d = col & 63;
          int b_ = row / T2, t2 = row - b_*T2;
          size_t base = (size_t)(b_*NH + h)*T2 + t2;
          g.cache[base*128 + (mode == 2 ? 64 : 0) + d] = vv;
          (mode == 1 ? g.katt : g.vatt)[base*64 + d] = f2b(vv);
        } else {
          if (row < NPLOC){
            int h = col >> 6, d = col & 63;
            g.patt[((size_t)h*NPLOC + row)*64 + d] = f2b(vv);
          }
        }
      }
    }
  }
}

// ---------------- output GEMM ----------------
__global__ __launch_bounds__(256) void gemm_out(const u16* __restrict__ A, const u16* __restrict__ W,
                                                const float* __restrict__ bias, float* __restrict__ out){
  int bid0 = blockIdx.x;
  int bid = (bid0 & 7) * 16 + (bid0 >> 3);   // 128 = 8*16
  int m0 = (bid >> 3) * 128, n0 = (bid & 7) * 128;
  int tid = threadIdx.x;
  f32x4 acc[4][4] = {};
  gemm_core(A, W, m0, n0, tid, acc);
  int lane = tid & 63;
  int wr = (tid >> 6) >> 1, wc = (tid >> 6) & 1;
  const int lr = lane & 15;
  #pragma unroll
  for (int m = 0; m < 4; ++m)
    #pragma unroll
    for (int n = 0; n < 4; ++n)
      #pragma unroll
      for (int j = 0; j < 4; ++j){
        int row = m0 + wr*64 + m*16 + (lane >> 4)*4 + j;
        int col = n0 + wc*64 + n*16 + lr;
        out[(size_t)row*1024 + col] = acc[m][n][j] + bias[col];
      }
}

// ---------------- attention (unchanged structure + T5 setprio) ----------------
__global__ __launch_bounds__(256, 2) void attn_v2(
    const u16* __restrict__ qu, const u16* __restrict__ qv,
    const u16* __restrict__ katt, const u16* __restrict__ vatt,
    const u16* __restrict__ patt, u16* __restrict__ xout)
{
  __shared__ __align__(16) u16 SB[64*384];    // 49152 B
  __shared__ __align__(16) u16 STG[14336];    // 28672 B staging
  int tid = threadIdx.x, lane = tid & 63, w = tid >> 6;
  int bid0 = blockIdx.x;
  int bid = (bid0 & 7) * 64 + (bid0 >> 3);    // XCD swizzle (512 = 8*64)
  int c = bid & 7, h = (bid >> 3) & 15, b = bid >> 7;
  int bh = b*NH + h;
  const int lr = lane & 15, g = lane >> 4, lk = g * 8;

  auto sb_off = [&](int r, int cc) -> uint32_t {
    return ((uint32_t)(r*384 + cc)*2) ^ ((uint32_t)(r & 15) << 4);
  };
  auto stg_swz = [&](uint32_t o) -> uint32_t { return o ^ (((o >> 7) & 7u) << 4); };
  auto vt_off = [&](int d, int kk) -> uint32_t {
    return ((uint32_t)(d*192 + kk)*2) ^ ((uint32_t)(((d & 7) ^ ((d >> 3) & 7))) << 4);
  };

  int qrow = 16*w + lr;
  const u16* qub = qu + ((size_t)bh*T1 + c*64 + qrow)*64;
  const u16* qvb = qv + ((size_t)bh*T1 + c*64 + qrow)*64;
  short8 qu0 = *(const short8*)(qub + lk);
  short8 qu1 = *(const short8*)(qub + 32 + lk);
  short8 qv0 = *(const short8*)(qvb + lk);
  short8 qv1 = *(const short8*)(qvb + 32 + lk);

  // ---- BD ----
  const char* psrc = (const char*)(patt + (size_t)h*NPLOC*64);
  for (int pc = 0; pc < 2; ++pc){
    #pragma unroll
    for (int i = 0; i < 7; ++i){
      uint32_t o = (uint32_t)(i*256 + tid)*16;
      async16(psrc + pc*28672 + stg_swz(o), (char*)STG + o);
    }
    __syncthreads();
    for (int nt = 0; nt < 14; ++nt){
      uint32_t bo = (uint32_t)((nt*16 + lr)*64)*2;
      short8 b0 = *(const short8*)((const char*)STG + stg_swz(bo + lk*2));
      short8 b1 = *(const short8*)((const char*)STG + stg_swz(bo + (32 + lk)*2));
      f32x4 acc = {0.f,0.f,0.f,0.f};
      __builtin_amdgcn_s_setprio(1);
      acc = __builtin_amdgcn_mfma_f32_16x16x32_bf16(qv0, b0, acc, 0, 0, 0);
      acc = __builtin_amdgcn_mfma_f32_16x16x32_bf16(qv1, b1, acc, 0, 0, 0);
      __builtin_amdgcn_s_setprio(0);
      int nl = pc*224 + nt*16 + lr;
      #pragma unroll
      for (int j = 0; j < 4; ++j){
        int r = 16*w + g*4 + j;
        int jj = nl + r - 63;
        if (jj >= 0 && jj < 384) *(u16*)((char*)SB + sb_off(r, jj)) = f2b(acc[j]);
      }
    }
    __syncthreads();
  }

  // ---- AC ----
  const char* ksrc = (const char*)(katt + ((size_t)bh*T2 + c*64)*64);
  f32x4 accs[24];
  #pragma unroll
  for (int t = 0; t < 24; ++t) accs[t] = (f32x4){0.f,0.f,0.f,0.f};
  #pragma unroll
  for (int kc = 0; kc < 2; ++kc){
    #pragma unroll
    for (int i = 0; i < 6; ++i){
      uint32_t o = (uint32_t)(i*256 + tid)*16;
      async16(ksrc + kc*24576 + stg_swz(o), (char*)STG + o);
    }
    __syncthreads();
    #pragma unroll
    for (int nt = 0; nt < 12; ++nt){
      uint32_t bo = (uint32_t)((nt*16 + lr)*64)*2;
      short8 b0 = *(const short8*)((const char*)STG + stg_swz(bo + lk*2));
      short8 b1 = *(const short8*)((const char*)STG + stg_swz(bo + (32 + lk)*2));
      int t = kc*12 + nt;
      __builtin_amdgcn_s_setprio(1);
      accs[t] = __builtin_amdgcn_mfma_f32_16x16x32_bf16(qu0, b0, accs[t], 0, 0, 0);
      accs[t] = __builtin_amdgcn_mfma_f32_16x16x32_bf16(qu1, b1, accs[t], 0, 0, 0);
      __builtin_amdgcn_s_setprio(0);
    }
    __syncthreads();
  }

  // ---- add bd, softmax in registers, P back to SB ----
  #pragma unroll
  for (int t = 0; t < 24; ++t)
    #pragma unroll
    for (int j = 0; j < 4; ++j){
      int r = 16*w + g*4 + j, cc = t*16 + lr;
      accs[t][j] += b2f(*(const u16*)((const char*)SB + sb_off(r, cc)));
    }
  float mx[4] = {-1e30f,-1e30f,-1e30f,-1e30f};
  #pragma unroll
  for (int t = 0; t < 24; ++t)
    #pragma unroll
    for (int j = 0; j < 4; ++j) mx[j] = fmaxf(mx[j], accs[t][j]);
  #pragma unroll
  for (int j = 0; j < 4; ++j){
    mx[j] = fmaxf(mx[j], __shfl_xor(mx[j], 1));
    mx[j] = fmaxf(mx[j], __shfl_xor(mx[j], 2));
    mx[j] = fmaxf(mx[j], __shfl_xor(mx[j], 4));
    mx[j] = fmaxf(mx[j], __shfl_xor(mx[j], 8));
  }
  float sm[4] = {0.f,0.f,0.f,0.f};
  #pragma unroll
  for (int t = 0; t < 24; ++t)
    #pragma unroll
    for (int j = 0; j < 4; ++j){
      accs[t][j] = __expf((accs[t][j] - mx[j]) * 0.125f);
      sm[j] += accs[t][j];
    }
  #pragma unroll
  for (int j = 0; j < 4; ++j){
    sm[j] += __shfl_xor(sm[j], 1);
    sm[j] += __shfl_xor(sm[j], 2);
    sm[j] += __shfl_xor(sm[j], 4);
    sm[j] += __shfl_xor(sm[j], 8);
    sm[j] = 1.f / sm[j];
  }
  #pragma unroll
  for (int t = 0; t < 24; ++t)
    #pragma unroll
    for (int j = 0; j < 4; ++j){
      int r = 16*w + g*4 + j, cc = t*16 + lr;
      *(u16*)((char*)SB + sb_off(r, cc)) = f2b(accs[t][j] * sm[j]);
    }
  __syncthreads();

  // ---- PV ----
  f32x4 acco[4] = {};
  #pragma unroll
  for (int vc = 0; vc < 2; ++vc){
    if (vc) __syncthreads();
    const u16* vb = vatt + ((size_t)bh*T2 + c*64 + vc*192)*64;
    #pragma unroll
    for (int i = 0; i < 6; ++i){
      int e = (i*256 + tid)*8;
      int kk = e >> 6, d0 = e & 63;
      uint4 vv4 = *(const uint4*)(vb + (size_t)kk*64 + d0);
      u16 uu[8] = { (u16)(vv4.x & 0xffff), (u16)(vv4.x >> 16), (u16)(vv4.y & 0xffff), (u16)(vv4.y >> 16),
                    (u16)(vv4.z & 0xffff), (u16)(vv4.z >> 16), (u16)(vv4.w & 0xffff), (u16)(vv4.w >> 16) };
      #pragma unroll
      for (int j = 0; j < 8; ++j)
        *(u16*)((char*)STG + vt_off(d0 + j, kk)) = uu[j];
    }
    __syncthreads();
    #pragma unroll
    for (int kt = 0; kt < 6; ++kt){
      short8 a = *(const short8*)((const char*)SB + sb_off(16*w + lr, vc*192 + kt*32 + lk));
      __builtin_amdgcn_s_setprio(1);
      #pragma unroll
      for (int n = 0; n < 4; ++n){
        short8 bb = *(const short8*)((const char*)STG + vt_off(n*16 + lr, kt*32 + lk));
        acco[n] = __builtin_amdgcn_mfma_f32_16x16x32_bf16(a, bb, acco[n], 0, 0, 0);
      }
      __builtin_amdgcn_s_setprio(0);
    }
  }

  #pragma unroll
  for (int n = 0; n < 4; ++n)
    #pragma unroll
    for (int j = 0; j < 4; ++j){
      int r = 16*w + g*4 + j;
      int t = c*64 + r, d = n*16 + lr;
      xout[((size_t)b*T1 + t)*1024 + h*64 + d] = f2b(acco[n][j]);
    }
}

// ---------------- launch ----------------
extern "C" void kernel_launch(void* const* d_in, const int* in_sizes, int n_in,
                              void* d_out, int out_size, void* d_ws, size_t ws_size,
                              hipStream_t stream)
{
  const float* query = (const float*)d_in[0];
  const float* key   = (const float*)d_in[1];
  const float* value = (const float*)d_in[2];
  const float* pos   = (const float*)d_in[3];
  const float* Wq  = (const float*)d_in[4];
  const float* bq  = (const float*)d_in[5];
  const float* Wk  = (const float*)d_in[6];
  const float* bk  = (const float*)d_in[7];
  const float* Wv  = (const float*)d_in[8];
  const float* bv  = (const float*)d_in[9];
  const float* Wp  = (const float*)d_in[10];
  const float* Wo  = (const float*)d_in[11];
  const float* bo  = (const float*)d_in[12];
  const float* pbu = (const float*)d_in[13];
  const float* pbv = (const float*)d_in[14];

  float* out   = (float*)d_out;
  float* cache = out + 2097152;

  u16* ws     = (u16*)d_ws;
  u16* q_bf   = ws;
  u16* key_bf = ws + 2097152;
  u16* val_bf = ws + 5505024;
  u16* pos_bf = ws + 8912896;
  u16* Wq_bf  = ws + 9437184;
  u16* Wk_bf  = ws + 10485760;
  u16* Wv_bf  = ws + 11534336;
  u16* Wp_bf  = ws + 12582912;
  u16* Wo_bf  = ws + 13631488;
  u16* qu_bf  = ws + 14680064;
  u16* qv_bf  = ws + 16777216;
  u16* katt   = ws + 18874368;
  u16* vatt   = ws + 22282240;
  u16* patt   = ws + 25690112;
  u16* x_bf   = ws + 26148864;

  CvtArgs ca;
  ca.s[0] = { query,            q_bf,   2048 };
  ca.s[1] = { key,              key_bf, 3328 };
  ca.s[2] = { value,            val_bf, 3328 };
  ca.s[3] = { Wq,               Wq_bf,  1024 };
  ca.s[4] = { Wk,               Wk_bf,  1024 };
  ca.s[5] = { Wv,               Wv_bf,  1024 };
  ca.s[6] = { Wp,               Wp_bf,  1024 };
  ca.s[7] = { Wo,               Wo_bf,  1024 };
  ca.s[8] = { pos + 448*1024,   pos_bf, 448 };
  cvt_all<<<14272, 256, 0, stream>>>(ca);

  G4Args ga;
  ga.q = q_bf; ga.k = key_bf; ga.v = val_bf; ga.p = pos_bf;
  ga.Wq = Wq_bf; ga.Wk = Wk_bf; ga.Wv = Wv_bf; ga.Wp = Wp_bf;
  ga.bq = bq; ga.bk = bk; ga.bv = bv; ga.pbu = pbu; ga.pbv = pbv;
  ga.qu = qu_bf; ga.qv2 = qv_bf; ga.katt = katt; ga.vatt = vatt; ga.patt = patt;
  ga.cache = cache;
  gemm4<<<576, 256, 0, stream>>>(ga);

  attn_v2<<<512, 256, 0, stream>>>(qu_bf, qv_bf, katt, vatt, patt, x_bf);

  gemm_out<<<128, 256, 0, stream>>>(x_bf, Wo_bf, bo, out);
}

// Round 4
// 94.701 us; speedup vs baseline: 1.9601x; 1.2339x over previous
//
#include <hip/hip_runtime.h>
#include <cstdint>

typedef unsigned short u16;
using short8 = __attribute__((ext_vector_type(8))) short;
using f32x4  = __attribute__((ext_vector_type(4))) float;

#define T1 512
#define T2 832
#define NH 16
#define NPLOC 448

__device__ __forceinline__ u16 f2b(float f){
  union { float f; uint32_t u; } c; c.f = f;
  uint32_t u = c.u;
  u += 0x7fffu + ((u >> 16) & 1u);   // RNE bf16
  return (u16)(u >> 16);
}
__device__ __forceinline__ float b2f(u16 b){
  union { uint32_t u; float f; } c; c.u = (uint32_t)b << 16; return c.f;
}
__device__ __forceinline__ void async16(const void* g, void* l){
  __builtin_amdgcn_global_load_lds(
      (const __attribute__((address_space(1))) unsigned int*)g,
      (__attribute__((address_space(3))) unsigned int*)l, 16, 0, 0);
}

// ---------------- fused f32 -> bf16 convert (one launch) ----------------
struct CvtSeg { const float* src; u16* dst; int nblk; };
struct CvtArgs { CvtSeg s[9]; };

__global__ __launch_bounds__(256) void cvt_all(CvtArgs a){
  int rel = blockIdx.x, seg = 0;
  while (rel >= a.s[seg].nblk){ rel -= a.s[seg].nblk; ++seg; }
  int i = rel * 256 + threadIdx.x;
  float4 v = ((const float4*)a.s[seg].src)[i];
  uint64_t p = (uint64_t)f2b(v.x) | ((uint64_t)f2b(v.y) << 16)
             | ((uint64_t)f2b(v.z) << 32) | ((uint64_t)f2b(v.w) << 48);
  *(uint64_t*)(a.s[seg].dst + (size_t)i * 4) = p;
}

// ---------------- counted-vmcnt pipelined GEMM core ----------------
// C-tile 64x128, BK=32, double-buffered, loads in flight across barriers.
// LDS tiles [rows][32] u16 with slot-XOR swizzle: slot ^= (row>>1)&3
// (applied to BOTH the global_load_lds source and the ds_read address).
__device__ __forceinline__ void gemm_core64(const u16* __restrict__ A, const u16* __restrict__ W,
    int m0, int n0, int tid, f32x4 acc[4][2])
{
  __shared__ __align__(16) u16 As0[2048];
  __shared__ __align__(16) u16 As1[2048];
  __shared__ __align__(16) u16 Bs0[4096];
  __shared__ __align__(16) u16 Bs1[4096];

  int lane = tid & 63, wc = tid >> 6;
  const int lr = lane & 15, g = lane >> 4;
  const int sslot = (g ^ ((lr >> 1) & 3)) * 8;          // read-side swizzled slot (u16)

  int r = tid >> 2;
  int ssl = ((tid & 3) ^ ((tid >> 3) & 3)) * 8;          // stage-source swizzled slot (u16)
  const u16* Asrc = A + (size_t)(m0 + r) * 1024 + ssl;
  const u16* Bsrc = W + (size_t)(n0 + r) * 1024 + ssl;

  auto stage = [&](int k0, u16* as, u16* bs){
    async16(Asrc + k0, as + tid*8);
    async16(Bsrc + k0, bs + tid*8);
    async16(Bsrc + 65536 + k0, bs + 2048 + tid*8);       // B rows +64
  };

  auto step = [&](u16* as, u16* bs, int kstage, bool do_stage, bool last){
    if (last) asm volatile("s_waitcnt vmcnt(0)" ::: "memory");
    else      asm volatile("s_waitcnt vmcnt(3)" ::: "memory");   // cur's 3 done, nxt's 3 in flight
    __builtin_amdgcn_sched_barrier(0);
    __builtin_amdgcn_s_barrier();                         // all waves: cur tile resident
    __builtin_amdgcn_sched_barrier(0);
    short8 a[4], b[2];
    #pragma unroll
    for (int m = 0; m < 4; ++m) a[m] = *(const short8*)&as[(m*16 + lr)*32 + sslot];
    #pragma unroll
    for (int n = 0; n < 2; ++n) b[n] = *(const short8*)&bs[(wc*32 + n*16 + lr)*32 + sslot];
    asm volatile("s_waitcnt lgkmcnt(0)" ::: "memory");
    __builtin_amdgcn_sched_barrier(0);
    __builtin_amdgcn_s_barrier();                         // all waves done reading cur
    __builtin_amdgcn_sched_barrier(0);
    if (do_stage) stage(kstage, as, bs);                  // overwrite cur; overlaps MFMA
    __builtin_amdgcn_sched_barrier(0);
    __builtin_amdgcn_s_setprio(1);
    #pragma unroll
    for (int m = 0; m < 4; ++m)
      #pragma unroll
      for (int n = 0; n < 2; ++n)
        acc[m][n] = __builtin_amdgcn_mfma_f32_16x16x32_bf16(a[m], b[n], acc[m][n], 0, 0, 0);
    __builtin_amdgcn_s_setprio(0);
  };

  stage(0, As0, Bs0);
  stage(32, As1, Bs1);
  __builtin_amdgcn_sched_barrier(0);
  for (int it = 0; it < 16; ++it){
    step(As0, Bs0, it*64 + 64, it < 15, false);
    step(As1, Bs1, it*64 + 96, it < 15, it == 15);
  }
}

// ---------------- fused q/k/v/pos projection GEMMs (1144 blocks) ----------------
struct G4Args {
  const u16 *q, *k, *v, *p;
  const u16 *Wq, *Wk, *Wv, *Wp;
  const float *bq, *bk, *bv, *pbu, *pbv;
  u16 *qu, *qv2, *katt, *vatt, *patt;
  float *cache;
};

__global__ __launch_bounds__(256, 4) void gemm4(G4Args ga){
  int bid0 = blockIdx.x;
  int bid = (bid0 & 7) * 143 + (bid0 >> 3);   // XCD swizzle (1144 = 8*143)
  int tid = threadIdx.x;
  int mode, mb; const u16 *A, *W;
  if (bid < 256)       { mode = 0; mb = bid >> 3;          A = ga.q; W = ga.Wq; }
  else if (bid < 672)  { mode = 1; mb = (bid - 256) >> 3;  A = ga.k; W = ga.Wk; }
  else if (bid < 1088) { mode = 2; mb = (bid - 672) >> 3;  A = ga.v; W = ga.Wv; }
  else                 { mode = 3; mb = (bid - 1088) >> 3; A = ga.p; W = ga.Wp; }
  int m0 = mb * 64, n0 = (bid & 7) * 128;
  f32x4 acc[4][2] = {};
  gemm_core64(A, W, m0, n0, tid, acc);

  int lane = tid & 63, wc = tid >> 6;
  const int lr = lane & 15, g = lane >> 4;
  #pragma unroll
  for (int m = 0; m < 4; ++m){
    #pragma unroll
    for (int n = 0; n < 2; ++n){
      #pragma unroll
      for (int j = 0; j < 4; ++j){
        int row = m0 + m*16 + g*4 + j;
        int col = n0 + wc*32 + n*16 + lr;
        float vv = acc[m][n][j];
        if (mode == 0){
          vv += ga.bq[col];
          int h = col >> 6, d = col & 63, b_ = row >> 9, t = row & 511;
          size_t o = ((size_t)((b_*NH + h)*T1 + t))*64 + d;
          ga.qu [o] = f2b(vv + ga.pbu[col]);
          ga.qv2[o] = f2b(vv + ga.pbv[col]);
        } else if (mode == 1 || mode == 2){
          vv += (mode == 1 ? ga.bk : ga.bv)[col];
          int h = col >> 6, d = col & 63;
          int b_ = row / T2, t2 = row - b_*T2;
          size_t base = (size_t)(b_*NH + h)*T2 + t2;
          ga.cache[base*128 + (mode == 2 ? 64 : 0) + d] = vv;
          (mode == 1 ? ga.katt : ga.vatt)[base*64 + d] = f2b(vv);
        } else {
          int h = col >> 6, d = col & 63;
          ga.patt[((size_t)h*NPLOC + row)*64 + d] = f2b(vv);
        }
      }
    }
  }
}

// ---------------- output GEMM (256 blocks) ----------------
__global__ __launch_bounds__(256, 4) void gemm_out(const u16* __restrict__ A, const u16* __restrict__ W,
                                                   const float* __restrict__ bias, float* __restrict__ out){
  int bid0 = blockIdx.x;
  int bid = (bid0 & 7) * 32 + (bid0 >> 3);   // 256 = 8*32
  int m0 = (bid >> 3) * 64, n0 = (bid & 7) * 128;
  int tid = threadIdx.x;
  f32x4 acc[4][2] = {};
  gemm_core64(A, W, m0, n0, tid, acc);
  int lane = tid & 63, wc = tid >> 6;
  const int lr = lane & 15, g = lane >> 4;
  #pragma unroll
  for (int m = 0; m < 4; ++m)
    #pragma unroll
    for (int n = 0; n < 2; ++n)
      #pragma unroll
      for (int j = 0; j < 4; ++j){
        int row = m0 + m*16 + g*4 + j;
        int col = n0 + wc*32 + n*16 + lr;
        out[(size_t)row*1024 + col] = acc[m][n][j] + bias[col];
      }
}

// ---------------- attention (unchanged from round 2/3) ----------------
__global__ __launch_bounds__(256, 2) void attn_v2(
    const u16* __restrict__ qu, const u16* __restrict__ qv,
    const u16* __restrict__ katt, const u16* __restrict__ vatt,
    const u16* __restrict__ patt, u16* __restrict__ xout)
{
  __shared__ __align__(16) u16 SB[64*384];    // 49152 B
  __shared__ __align__(16) u16 STG[14336];    // 28672 B staging
  int tid = threadIdx.x, lane = tid & 63, w = tid >> 6;
  int bid0 = blockIdx.x;
  int bid = (bid0 & 7) * 64 + (bid0 >> 3);    // XCD swizzle (512 = 8*64)
  int c = bid & 7, h = (bid >> 3) & 15, b = bid >> 7;
  int bh = b*NH + h;
  const int lr = lane & 15, g = lane >> 4, lk = g * 8;

  auto sb_off = [&](int r, int cc) -> uint32_t {
    return ((uint32_t)(r*384 + cc)*2) ^ ((uint32_t)(r & 15) << 4);
  };
  auto stg_swz = [&](uint32_t o) -> uint32_t { return o ^ (((o >> 7) & 7u) << 4); };
  auto vt_off = [&](int d, int kk) -> uint32_t {
    return ((uint32_t)(d*192 + kk)*2) ^ ((uint32_t)(((d & 7) ^ ((d >> 3) & 7))) << 4);
  };

  int qrow = 16*w + lr;
  const u16* qub = qu + ((size_t)bh*T1 + c*64 + qrow)*64;
  const u16* qvb = qv + ((size_t)bh*T1 + c*64 + qrow)*64;
  short8 qu0 = *(const short8*)(qub + lk);
  short8 qu1 = *(const short8*)(qub + 32 + lk);
  short8 qv0 = *(const short8*)(qvb + lk);
  short8 qv1 = *(const short8*)(qvb + 32 + lk);

  // ---- BD ----
  const char* psrc = (const char*)(patt + (size_t)h*NPLOC*64);
  for (int pc = 0; pc < 2; ++pc){
    #pragma unroll
    for (int i = 0; i < 7; ++i){
      uint32_t o = (uint32_t)(i*256 + tid)*16;
      async16(psrc + pc*28672 + stg_swz(o), (char*)STG + o);
    }
    __syncthreads();
    for (int nt = 0; nt < 14; ++nt){
      uint32_t bo = (uint32_t)((nt*16 + lr)*64)*2;
      short8 b0 = *(const short8*)((const char*)STG + stg_swz(bo + lk*2));
      short8 b1 = *(const short8*)((const char*)STG + stg_swz(bo + (32 + lk)*2));
      f32x4 acc = {0.f,0.f,0.f,0.f};
      __builtin_amdgcn_s_setprio(1);
      acc = __builtin_amdgcn_mfma_f32_16x16x32_bf16(qv0, b0, acc, 0, 0, 0);
      acc = __builtin_amdgcn_mfma_f32_16x16x32_bf16(qv1, b1, acc, 0, 0, 0);
      __builtin_amdgcn_s_setprio(0);
      int nl = pc*224 + nt*16 + lr;
      #pragma unroll
      for (int j = 0; j < 4; ++j){
        int r = 16*w + g*4 + j;
        int jj = nl + r - 63;
        if (jj >= 0 && jj < 384) *(u16*)((char*)SB + sb_off(r, jj)) = f2b(acc[j]);
      }
    }
    __syncthreads();
  }

  // ---- AC ----
  const char* ksrc = (const char*)(katt + ((size_t)bh*T2 + c*64)*64);
  f32x4 accs[24];
  #pragma unroll
  for (int t = 0; t < 24; ++t) accs[t] = (f32x4){0.f,0.f,0.f,0.f};
  #pragma unroll
  for (int kc = 0; kc < 2; ++kc){
    #pragma unroll
    for (int i = 0; i < 6; ++i){
      uint32_t o = (uint32_t)(i*256 + tid)*16;
      async16(ksrc + kc*24576 + stg_swz(o), (char*)STG + o);
    }
    __syncthreads();
    #pragma unroll
    for (int nt = 0; nt < 12; ++nt){
      uint32_t bo = (uint32_t)((nt*16 + lr)*64)*2;
      short8 b0 = *(const short8*)((const char*)STG + stg_swz(bo + lk*2));
      short8 b1 = *(const short8*)((const char*)STG + stg_swz(bo + (32 + lk)*2));
      int t = kc*12 + nt;
      __builtin_amdgcn_s_setprio(1);
      accs[t] = __builtin_amdgcn_mfma_f32_16x16x32_bf16(qu0, b0, accs[t], 0, 0, 0);
      accs[t] = __builtin_amdgcn_mfma_f32_16x16x32_bf16(qu1, b1, accs[t], 0, 0, 0);
      __builtin_amdgcn_s_setprio(0);
    }
    __syncthreads();
  }

  // ---- add bd, softmax in registers, P back to SB ----
  #pragma unroll
  for (int t = 0; t < 24; ++t)
    #pragma unroll
    for (int j = 0; j < 4; ++j){
      int r = 16*w + g*4 + j, cc = t*16 + lr;
      accs[t][j] += b2f(*(const u16*)((const char*)SB + sb_off(r, cc)));
    }
  float mx[4] = {-1e30f,-1e30f,-1e30f,-1e30f};
  #pragma unroll
  for (int t = 0; t < 24; ++t)
    #pragma unroll
    for (int j = 0; j < 4; ++j) mx[j] = fmaxf(mx[j], accs[t][j]);
  #pragma unroll
  for (int j = 0; j < 4; ++j){
    mx[j] = fmaxf(mx[j], __shfl_xor(mx[j], 1));
    mx[j] = fmaxf(mx[j], __shfl_xor(mx[j], 2));
    mx[j] = fmaxf(mx[j], __shfl_xor(mx[j], 4));
    mx[j] = fmaxf(mx[j], __shfl_xor(mx[j], 8));
  }
  float sm[4] = {0.f,0.f,0.f,0.f};
  #pragma unroll
  for (int t = 0; t < 24; ++t)
    #pragma unroll
    for (int j = 0; j < 4; ++j){
      accs[t][j] = __expf((accs[t][j] - mx[j]) * 0.125f);
      sm[j] += accs[t][j];
    }
  #pragma unroll
  for (int j = 0; j < 4; ++j){
    sm[j] += __shfl_xor(sm[j], 1);
    sm[j] += __shfl_xor(sm[j], 2);
    sm[j] += __shfl_xor(sm[j], 4);
    sm[j] += __shfl_xor(sm[j], 8);
    sm[j] = 1.f / sm[j];
  }
  #pragma unroll
  for (int t = 0; t < 24; ++t)
    #pragma unroll
    for (int j = 0; j < 4; ++j){
      int r = 16*w + g*4 + j, cc = t*16 + lr;
      *(u16*)((char*)SB + sb_off(r, cc)) = f2b(accs[t][j] * sm[j]);
    }
  __syncthreads();

  // ---- PV ----
  f32x4 acco[4] = {};
  #pragma unroll
  for (int vc = 0; vc < 2; ++vc){
    if (vc) __syncthreads();
    const u16* vb = vatt + ((size_t)bh*T2 + c*64 + vc*192)*64;
    #pragma unroll
    for (int i = 0; i < 6; ++i){
      int e = (i*256 + tid)*8;
      int kk = e >> 6, d0 = e & 63;
      uint4 vv4 = *(const uint4*)(vb + (size_t)kk*64 + d0);
      u16 uu[8] = { (u16)(vv4.x & 0xffff), (u16)(vv4.x >> 16), (u16)(vv4.y & 0xffff), (u16)(vv4.y >> 16),
                    (u16)(vv4.z & 0xffff), (u16)(vv4.z >> 16), (u16)(vv4.w & 0xffff), (u16)(vv4.w >> 16) };
      #pragma unroll
      for (int j = 0; j < 8; ++j)
        *(u16*)((char*)STG + vt_off(d0 + j, kk)) = uu[j];
    }
    __syncthreads();
    #pragma unroll
    for (int kt = 0; kt < 6; ++kt){
      short8 a = *(const short8*)((const char*)SB + sb_off(16*w + lr, vc*192 + kt*32 + lk));
      __builtin_amdgcn_s_setprio(1);
      #pragma unroll
      for (int n = 0; n < 4; ++n){
        short8 bb = *(const short8*)((const char*)STG + vt_off(n*16 + lr, kt*32 + lk));
        acco[n] = __builtin_amdgcn_mfma_f32_16x16x32_bf16(a, bb, acco[n], 0, 0, 0);
      }
      __builtin_amdgcn_s_setprio(0);
    }
  }

  #pragma unroll
  for (int n = 0; n < 4; ++n)
    #pragma unroll
    for (int j = 0; j < 4; ++j){
      int r = 16*w + g*4 + j;
      int t = c*64 + r, d = n*16 + lr;
      xout[((size_t)b*T1 + t)*1024 + h*64 + d] = f2b(acco[n][j]);
    }
}

// ---------------- launch ----------------
extern "C" void kernel_launch(void* const* d_in, const int* in_sizes, int n_in,
                              void* d_out, int out_size, void* d_ws, size_t ws_size,
                              hipStream_t stream)
{
  const float* query = (const float*)d_in[0];
  const float* key   = (const float*)d_in[1];
  const float* value = (const float*)d_in[2];
  const float* pos   = (const float*)d_in[3];
  const float* Wq  = (const float*)d_in[4];
  const float* bq  = (const float*)d_in[5];
  const float* Wk  = (const float*)d_in[6];
  const float* bk  = (const float*)d_in[7];
  const float* Wv  = (const float*)d_in[8];
  const float* bv  = (const float*)d_in[9];
  const float* Wp  = (const float*)d_in[10];
  const float* Wo  = (const float*)d_in[11];
  const float* bo  = (const float*)d_in[12];
  const float* pbu = (const float*)d_in[13];
  const float* pbv = (const float*)d_in[14];

  float* out   = (float*)d_out;
  float* cache = out + 2097152;

  u16* ws     = (u16*)d_ws;
  u16* q_bf   = ws;
  u16* key_bf = ws + 2097152;
  u16* val_bf = ws + 5505024;
  u16* pos_bf = ws + 8912896;
  u16* Wq_bf  = ws + 9437184;
  u16* Wk_bf  = ws + 10485760;
  u16* Wv_bf  = ws + 11534336;
  u16* Wp_bf  = ws + 12582912;
  u16* Wo_bf  = ws + 13631488;
  u16* qu_bf  = ws + 14680064;
  u16* qv_bf  = ws + 16777216;
  u16* katt   = ws + 18874368;
  u16* vatt   = ws + 22282240;
  u16* patt   = ws + 25690112;
  u16* x_bf   = ws + 26148864;

  CvtArgs ca;
  ca.s[0] = { query,            q_bf,   2048 };
  ca.s[1] = { key,              key_bf, 3328 };
  ca.s[2] = { value,            val_bf, 3328 };
  ca.s[3] = { Wq,               Wq_bf,  1024 };
  ca.s[4] = { Wk,               Wk_bf,  1024 };
  ca.s[5] = { Wv,               Wv_bf,  1024 };
  ca.s[6] = { Wp,               Wp_bf,  1024 };
  ca.s[7] = { Wo,               Wo_bf,  1024 };
  ca.s[8] = { pos + 448*1024,   pos_bf, 448 };
  cvt_all<<<14272, 256, 0, stream>>>(ca);

  G4Args ga;
  ga.q = q_bf; ga.k = key_bf; ga.v = val_bf; ga.p = pos_bf;
  ga.Wq = Wq_bf; ga.Wk = Wk_bf; ga.Wv = Wv_bf; ga.Wp = Wp_bf;
  ga.bq = bq; ga.bk = bk; ga.bv = bv; ga.pbu = pbu; ga.pbv = pbv;
  ga.qu = qu_bf; ga.qv2 = qv_bf; ga.katt = katt; ga.vatt = vatt; ga.patt = patt;
  ga.cache = cache;
  gemm4<<<1144, 256, 0, stream>>>(ga);

  attn_v2<<<512, 256, 0, stream>>>(qu_bf, qv_bf, katt, vatt, patt, x_bf);

  gemm_out<<<256, 256, 0, stream>>>(x_bf, Wo_bf, bo, out);
}